// Round 9
// baseline (4902.309 us; speedup 1.0000x reference)
//
#include <hip/hip_runtime.h>
#include <stdint.h>

// ScannedRNN: T=1024, B=128, D=512 GRU with resets + straight-through clip.
// prep (weight pack) -> rnnB single persistent launch: 128 blocks = 16 col x
// 8 row groups; Wi+Wh slices in VGPRs; x@Wi computed OFF the critical path
// (during the h poll window); h exchanged as tagged bf16 words
// (epoch<<16|bf16), 2-slot parity, relaxed agent scope (r5-proven protocol);
// row-segment ownership -> vectorized poll (8x u64) and staging (2x uint4).

typedef float f32x4 __attribute__((ext_vector_type(4)));
typedef short s16x8 __attribute__((ext_vector_type(8)));

#define DD 512
#define BB 128
#define TT 1024

static __device__ __forceinline__ unsigned short f2bf(float f) {
  uint32_t u = __builtin_bit_cast(uint32_t, f);
  u = (u + 0x7fffu + ((u >> 16) & 1u)) >> 16;   // RNE
  return (unsigned short)u;
}
static __device__ __forceinline__ s16x8 ldsfrag(const char* p) {
  return __builtin_bit_cast(s16x8, *reinterpret_cast<const uint4*>(p));
}

// ---------------- prep: pack Wi and Wh slices, bf16, per-column-block ----------------
// Wipk/Wpk [cj][c96][k]: c96 = gate*32+cc; gate 0=r,1=z,2=n; k = 0..511.
__global__ void prep(const float* __restrict__ Wi, const float* __restrict__ Whrz,
                     const float* __restrict__ Whn,
                     unsigned short* __restrict__ Wipk, unsigned short* __restrict__ Wpk) {
  int i = blockIdx.x * 256 + threadIdx.x;
  if (i < 786432) {
    int ck = i >> 9, k = i & 511;
    int cj = ck / 96, c96 = ck % 96;
    int g = c96 >> 5, cc = c96 & 31;
    Wipk[i] = f2bf(Wi[(size_t)k * 1536 + g * 512 + cj * 32 + cc]);
  } else {
    int j = i - 786432;
    int ck = j >> 9, k = j & 511;
    int cj = ck / 96, c96 = ck % 96;
    int g = c96 >> 5, cc = c96 & 31;
    float v = (g < 2) ? Whrz[(size_t)k * 1024 + g * 512 + cj * 32 + cc]
                      : Whn[(size_t)k * 512 + cj * 32 + cc];
    Wpk[j] = f2bf(v);
  }
}

// ---------------- tag0: slot0 <- tagged(epoch 0) h0; f32 carry <- h0 ----------
__global__ void tag0(const float* __restrict__ h0, uint32_t* __restrict__ hxt,
                     float* __restrict__ hbF) {
  int i = blockIdx.x * 512 + threadIdx.x;   // 65536
  float v = h0[i];
  hxt[i] = (uint32_t)f2bf(v);               // tag 0
  hbF[i] = v;
}

// ---------------- resets dtype probe (bool bytes vs int32) ----------------
__global__ void scanR(const int* __restrict__ r, int* __restrict__ flag) {
  int i = blockIdx.x * 256 + threadIdx.x;       // 32768 ints = 131072 bytes, safe
  unsigned int v = (unsigned int)r[i];
  if (v > 1u) atomicOr(flag, 1);
}

// ---------------- helpers ----------------
static __device__ __forceinline__ unsigned rmask16f(const int* resets, int rmode,
                                                    long long tg, int row0) {
  unsigned m = 0;
  if (rmode) {
    const unsigned char* rb = reinterpret_cast<const unsigned char*>(resets);
    uint4 u = *reinterpret_cast<const uint4*>(rb + (size_t)tg * 128 + row0);
    unsigned w0 = u.x, w1 = u.y, w2 = u.z, w3 = u.w;
#pragma unroll
    for (int b = 0; b < 4; ++b) {
      if ((w0 >> (8 * b)) & 0xFFu) m |= 1u << (0 + b);
      if ((w1 >> (8 * b)) & 0xFFu) m |= 1u << (4 + b);
      if ((w2 >> (8 * b)) & 0xFFu) m |= 1u << (8 + b);
      if ((w3 >> (8 * b)) & 0xFFu) m |= 1u << (12 + b);
    }
  } else {
    const uint4* p = reinterpret_cast<const uint4*>(resets + (size_t)tg * 128 + row0);
#pragma unroll
    for (int q = 0; q < 4; ++q) {
      uint4 u = p[q];
      if (u.x) m |= 1u << (q * 4 + 0);
      if (u.y) m |= 1u << (q * 4 + 1);
      if (u.z) m |= 1u << (q * 4 + 2);
      if (u.w) m |= 1u << (q * 4 + 3);
    }
  }
  return m;
}

// batched tag poll, 64-bit atomic loads (2 words each), retry-masked.
// All 16 words come from ONE producer block (16-col segment within its 32).
static __device__ __forceinline__ void pollTagQ(const uint32_t* src, unsigned exp,
                                                unsigned short (&v)[16]) {
  const unsigned long long* s8 = reinterpret_cast<const unsigned long long*>(src);
  bool need = true;
  for (int it = 0; it < (1 << 14); ++it) {
    if (need) {
      unsigned long long q[8];
#pragma unroll
      for (int i = 0; i < 8; ++i)
        q[i] = __hip_atomic_load(s8 + i, __ATOMIC_RELAXED, __HIP_MEMORY_SCOPE_AGENT);
      unsigned bad = 0;
#pragma unroll
      for (int i = 0; i < 8; ++i)
        bad |= (unsigned)(((q[i] >> 16) ^ (unsigned long long)exp) & 0xFFFFull)
             | (unsigned)(((q[i] >> 48) ^ (unsigned long long)exp) & 0xFFFFull);
      if (bad == 0u) {
#pragma unroll
        for (int i = 0; i < 8; ++i) {
          v[2 * i]     = (unsigned short)q[i];
          v[2 * i + 1] = (unsigned short)(q[i] >> 32);
        }
        need = false;
      }
    }
    if (__ballot(need ? 1 : 0) == 0ull) break;
    if (it >= 1) __builtin_amdgcn_s_sleep(1);
  }
}

static __device__ __forceinline__ f32x4 mfbf(uint4 wfr, s16x8 b, f32x4 c) {
  return __builtin_amdgcn_mfma_f32_16x16x32_bf16(__builtin_bit_cast(s16x8, wfr), b, c, 0, 0, 0);
}

// ---------------- rnnB ----------------
#define RNN_SMEM (16384 + 16384 + 34816)   // Hlb + Xlb + ax[8][4][272]f32

__global__ __launch_bounds__(512) void rnnB(const float* __restrict__ x,
                                            const unsigned short* __restrict__ Wipk,
                                            const unsigned short* __restrict__ Wpk,
                                            const float* __restrict__ bi,
                                            const float* __restrict__ bhn,
                                            const int* __restrict__ resets,
                                            uint32_t* hxt,                 // [2][128][512]
                                            const float* __restrict__ hbF, // [128][512]
                                            const int* __restrict__ rmodep,
                                            float* __restrict__ ys,
                                            int tc) {
  extern __shared__ char smem[];
  char* Hlb = smem;                                       // 16384 B
  char* Xlb = smem + 16384;                               // 16384 B
  float* ax = reinterpret_cast<float*>(smem + 32768);     // 34816 B

  const int tid = threadIdx.x;
  const int lane = tid & 63;
  const int wv = tid >> 6;
  const int w = wv & 1, ks = wv >> 1;
  const int cj = blockIdx.x >> 3, rg = blockIdx.x & 7;
  const int ec = tid & 31, eb = tid >> 5;          // elementwise: col-in-32, row-in-16
  const int bglob = rg * 16 + eb;
  const int colglob = cj * 32 + ec;
  const int b16 = tid & 15, seg = tid >> 4;        // staging: row, 16-col segment
  const int swzB = (b16 & 7) << 4;
  const int soff0 = b16 * 1024 + ((seg * 32) ^ swzB);
  const int soff1 = b16 * 1024 + ((seg * 32 + 16) ^ swzB);
  const int rmode = *rmodep;

  // MFMA read geometry (B-operand: row = lane&15, k-slice by lane>>4)
  const int rowb = lane & 15;
  const int hsw = (rowb & 7) << 4;
  const int kplusB = (lane >> 4) << 4;

  // ---- Wh + Wi fragments -> registers (once per launch) ----
  uint4 wreg[3][4], wireg[3][4];
  {
    const size_t fb = (size_t)cj * 96 * 512
                    + (size_t)(w * 16 + (lane & 15)) * 512
                    + ks * 128 + (lane >> 4) * 8;
#pragma unroll
    for (int g = 0; g < 3; ++g)
#pragma unroll
      for (int kk = 0; kk < 4; ++kk) {
        wreg[g][kk]  = *reinterpret_cast<const uint4*>(Wpk  + fb + g * 32 * 512 + kk * 32);
        wireg[g][kk] = *reinterpret_cast<const uint4*>(Wipk + fb + g * 32 * 512 + kk * 32);
      }
  }

  const float bhn_c = bhn[colglob];
  float bir3[3];
#pragma unroll
  for (int g = 0; g < 3; ++g) bir3[g] = bi[g * 512 + colglob];
  float h_old = hbF[(size_t)bglob * 512 + colglob];

  // ---- preamble: x(0) -> Xlb -> xp*(0); prefetch x(1); poll h(0) ----
  float4 xq[4];
  {
    const float* xr = x + (size_t)(rg * 16 + b16) * 512 + seg * 16;
#pragma unroll
    for (int q = 0; q < 4; ++q) xq[q] = *reinterpret_cast<const float4*>(xr + q * 4);
  }
  {
    uint4 p0, p1;
    p0.x = (uint32_t)f2bf(xq[0].x) | ((uint32_t)f2bf(xq[0].y) << 16);
    p0.y = (uint32_t)f2bf(xq[0].z) | ((uint32_t)f2bf(xq[0].w) << 16);
    p0.z = (uint32_t)f2bf(xq[1].x) | ((uint32_t)f2bf(xq[1].y) << 16);
    p0.w = (uint32_t)f2bf(xq[1].z) | ((uint32_t)f2bf(xq[1].w) << 16);
    p1.x = (uint32_t)f2bf(xq[2].x) | ((uint32_t)f2bf(xq[2].y) << 16);
    p1.y = (uint32_t)f2bf(xq[2].z) | ((uint32_t)f2bf(xq[2].w) << 16);
    p1.z = (uint32_t)f2bf(xq[3].x) | ((uint32_t)f2bf(xq[3].y) << 16);
    p1.w = (uint32_t)f2bf(xq[3].z) | ((uint32_t)f2bf(xq[3].w) << 16);
    *reinterpret_cast<uint4*>(Xlb + soff0) = p0;
    *reinterpret_cast<uint4*>(Xlb + soff1) = p1;
  }
  __syncthreads();
  f32x4 xpR = (f32x4){0.f, 0.f, 0.f, 0.f}, xpZ = xpR, xpN = xpR;
  {
    s16x8 xf[4];
#pragma unroll
    for (int kk = 0; kk < 4; ++kk) {
      const int kbB = (ks * 128 + kk * 32) * 2 + kplusB;
      xf[kk] = ldsfrag(Xlb + rowb * 1024 + (kbB ^ hsw));
    }
#pragma unroll
    for (int kk = 0; kk < 4; ++kk) {
      xpR = mfbf(wireg[0][kk], xf[kk], xpR);
      xpZ = mfbf(wireg[1][kk], xf[kk], xpZ);
      xpN = mfbf(wireg[2][kk], xf[kk], xpN);
    }
  }
  if (tc > 1) {
    const float* xr = x + ((size_t)1 * 128 + rg * 16 + b16) * 512 + seg * 16;
#pragma unroll
    for (int q = 0; q < 4; ++q) xq[q] = *reinterpret_cast<const float4*>(xr + q * 4);
  }
  unsigned short v[16];
  pollTagQ(hxt + (size_t)(rg * 16 + b16) * 512 + seg * 16, 0u, v);
  unsigned mask = rmask16f(resets, rmode, 0, rg * 16);

  for (int t = 0; t < tc; ++t) {
    // ---- stage H(t): 2 uint4 writes, reset-masked (row-uniform bit) ----
    {
      const unsigned keep = ((mask >> b16) & 1u) ? 0u : 0xFFFFFFFFu;
      uint4 p0, p1;
      p0.x = ((uint32_t)v[0] | ((uint32_t)v[1] << 16)) & keep;
      p0.y = ((uint32_t)v[2] | ((uint32_t)v[3] << 16)) & keep;
      p0.z = ((uint32_t)v[4] | ((uint32_t)v[5] << 16)) & keep;
      p0.w = ((uint32_t)v[6] | ((uint32_t)v[7] << 16)) & keep;
      p1.x = ((uint32_t)v[8] | ((uint32_t)v[9] << 16)) & keep;
      p1.y = ((uint32_t)v[10] | ((uint32_t)v[11] << 16)) & keep;
      p1.z = ((uint32_t)v[12] | ((uint32_t)v[13] << 16)) & keep;
      p1.w = ((uint32_t)v[14] | ((uint32_t)v[15] << 16)) & keep;
      *reinterpret_cast<uint4*>(Hlb + soff0) = p0;
      *reinterpret_cast<uint4*>(Hlb + soff1) = p1;
    }
    __syncthreads();  // B1
    // ---- 12 H-MFMAs ----
    f32x4 hR = (f32x4){0.f, 0.f, 0.f, 0.f}, hZ = hR, hNH = hR;
    {
      s16x8 hf[4];
#pragma unroll
      for (int kk = 0; kk < 4; ++kk) {
        const int kbB = (ks * 128 + kk * 32) * 2 + kplusB;
        hf[kk] = ldsfrag(Hlb + rowb * 1024 + (kbB ^ hsw));
      }
#pragma unroll
      for (int kk = 0; kk < 4; ++kk) {
        hR = mfbf(wreg[0][kk], hf[kk], hR);
        hZ = mfbf(wreg[1][kk], hf[kk], hZ);
        hNH = mfbf(wreg[2][kk], hf[kk], hNH);
      }
    }
    {  // partials -> ax: planes R(sum), Z(sum), NX, NH; padded stride 17
      const int mh = (lane >> 4) << 2, nn = lane & 15;
      float* base = ax + (size_t)((ks * 2 + w) * 4) * 272 + nn;
      const f32x4 pR = hR + xpR, pZ = hZ + xpZ;
#pragma unroll
      for (int r = 0; r < 4; ++r) {
        base[(mh + r) * 17] = pR[r];
        base[272 + (mh + r) * 17] = pZ[r];
        base[544 + (mh + r) * 17] = xpN[r];
        base[816 + (mh + r) * 17] = hNH[r];
      }
    }
    __syncthreads();  // B2
    // ---- elementwise GRU update: one (row eb, col ec) per thread ----
    {
      const int wc = ec >> 4, mc = ec & 15;
      float s0 = 0.f, s1 = 0.f, s2x = 0.f, s2h = 0.f;
#pragma unroll
      for (int k2 = 0; k2 < 4; ++k2) {
        const float* p = ax + (size_t)((k2 * 2 + wc) * 4) * 272 + mc * 17 + eb;
        s0 += p[0]; s1 += p[272]; s2x += p[544]; s2h += p[816];
      }
      const float r = 1.f / (1.f + __expf(-(bir3[0] + s0)));
      const float z = 1.f / (1.f + __expf(-(bir3[1] + s1)));
      const float hu = ((mask >> eb) & 1u) ? 0.f : h_old;
      const float pre = (bir3[2] + s2x) + r * (s2h + bhn_c);
      const float n = 1.f - 2.f / (1.f + __expf(2.f * pre));
      float hn = (1.f - z) * n + z * hu;
      hn = fminf(1.f, fmaxf(-1.f, hn));
      // publish FIRST (critical path), then output store
      const uint32_t tagged = (((uint32_t)(t + 1) & 0xFFFFu) << 16) | (uint32_t)f2bf(hn);
      __hip_atomic_store(hxt + (size_t)((t + 1) & 1) * 65536 + (size_t)bglob * 512 + colglob,
                         tagged, __ATOMIC_RELAXED, __HIP_MEMORY_SCOPE_AGENT);
      __builtin_nontemporal_store(hn, ys + ((size_t)t * 128 + bglob) * 512 + colglob);
      h_old = hn;
    }
    if (t + 1 < tc) {
      const unsigned nmask = rmask16f(resets, rmode, t + 1, rg * 16);
      // ---- OFF-PATH: stage X(t+1), compute xp*(t+1) during peers' publish ----
      {
        uint4 p0, p1;
        p0.x = (uint32_t)f2bf(xq[0].x) | ((uint32_t)f2bf(xq[0].y) << 16);
        p0.y = (uint32_t)f2bf(xq[0].z) | ((uint32_t)f2bf(xq[0].w) << 16);
        p0.z = (uint32_t)f2bf(xq[1].x) | ((uint32_t)f2bf(xq[1].y) << 16);
        p0.w = (uint32_t)f2bf(xq[1].z) | ((uint32_t)f2bf(xq[1].w) << 16);
        p1.x = (uint32_t)f2bf(xq[2].x) | ((uint32_t)f2bf(xq[2].y) << 16);
        p1.y = (uint32_t)f2bf(xq[2].z) | ((uint32_t)f2bf(xq[2].w) << 16);
        p1.z = (uint32_t)f2bf(xq[3].x) | ((uint32_t)f2bf(xq[3].y) << 16);
        p1.w = (uint32_t)f2bf(xq[3].z) | ((uint32_t)f2bf(xq[3].w) << 16);
        *reinterpret_cast<uint4*>(Xlb + soff0) = p0;
        *reinterpret_cast<uint4*>(Xlb + soff1) = p1;
      }
      __syncthreads();  // B3
      {
        s16x8 xf[4];
#pragma unroll
        for (int kk = 0; kk < 4; ++kk) {
          const int kbB = (ks * 128 + kk * 32) * 2 + kplusB;
          xf[kk] = ldsfrag(Xlb + rowb * 1024 + (kbB ^ hsw));
        }
        xpR = (f32x4){0.f, 0.f, 0.f, 0.f}; xpZ = xpR; xpN = xpR;
#pragma unroll
        for (int kk = 0; kk < 4; ++kk) {
          xpR = mfbf(wireg[0][kk], xf[kk], xpR);
          xpZ = mfbf(wireg[1][kk], xf[kk], xpZ);
          xpN = mfbf(wireg[2][kk], xf[kk], xpN);
        }
      }
      if (t + 2 < tc) {  // prefetch x(t+2) (consumed next iter's off-path stage)
        const float* xr = x + ((size_t)(t + 2) * 128 + rg * 16 + b16) * 512 + seg * 16;
#pragma unroll
        for (int q = 0; q < 4; ++q) xq[q] = *reinterpret_cast<const float4*>(xr + q * 4);
      }
      // ---- poll h(t+1) ----
      pollTagQ(hxt + (size_t)((t + 1) & 1) * 65536 + (size_t)(rg * 16 + b16) * 512 + seg * 16,
               (unsigned)(t + 1) & 0xFFFFu, v);
      mask = nmask;
    }
  }
}

// ---------------- launch ----------------
extern "C" void kernel_launch(void* const* d_in, const int* in_sizes, int n_in,
                              void* d_out, int out_size, void* d_ws, size_t ws_size,
                              hipStream_t stream) {
  const float* h0 = (const float*)d_in[0];
  const float* ins = (const float*)d_in[1];
  const int* rst = (const int*)d_in[2];
  const float* Wi = (const float*)d_in[3];
  const float* bi = (const float*)d_in[4];
  const float* Whrz = (const float*)d_in[5];
  const float* Whn = (const float*)d_in[6];
  const float* bhn = (const float*)d_in[7];
  float* ys = (float*)d_out;

  char* ws = (char*)d_ws;
  unsigned short* Wpk = (unsigned short*)(ws);              // 1,572,864 B
  unsigned short* Wipk = (unsigned short*)(ws + 1572864);   // 1,572,864 B
  uint32_t* hxt = (uint32_t*)(ws + 3145728);                //   524,288 B ([2][128][512])
  float* hbF = (float*)(ws + 3670016);                      //   262,144 B
  int* flag = (int*)(ws + 3932160);                         //         4 B (rmode)

  hipMemsetAsync(flag, 0, 4, stream);                                  // rmode
  hipMemsetAsync(hxt, 0, 524288, stream);        // both slots -> tag 0 (replay-safe)
  tag0<<<dim3(128), dim3(512), 0, stream>>>(h0, hxt, hbF);             // slot0 = h(0)
  prep<<<dim3(6144), dim3(256), 0, stream>>>(Wi, Whrz, Whn, Wipk, Wpk);
  scanR<<<dim3(128), dim3(256), 0, stream>>>(rst, flag);
  hipFuncSetAttribute((const void*)rnnB, hipFuncAttributeMaxDynamicSharedMemorySize,
                      RNN_SMEM);
  rnnB<<<dim3(128), dim3(512), RNN_SMEM, stream>>>(ins, Wipk, Wpk, bi, bhn, rst,
                                                   hxt, hbF, flag, ys, 1024);
}

// Round 10
// 4289.629 us; speedup vs baseline: 1.1428x; 1.1428x over previous
//
#include <hip/hip_runtime.h>
#include <stdint.h>

// ScannedRNN: T=1024, B=128, D=512 GRU with resets + straight-through clip.
// prep (weight pack) -> rnnB single persistent launch: 128 blocks = 16 col x
// 8 row groups; Wi+Wh slices in VGPRs; x@Wi folded into the step (24 MFMAs
// between B1/B2); h exchanged as tagged bf16 words (epoch<<16|bf16), 2-slot
// parity, relaxed agent scope (r5-proven). Poll window (publish -> poll, NO
// barrier) holds X(t+1) staging + x(t+2) prefetch. ax reduce stride 18
// (conflict-free banks).

typedef float f32x4 __attribute__((ext_vector_type(4)));
typedef short s16x8 __attribute__((ext_vector_type(8)));

#define DD 512
#define BB 128
#define TT 1024

static __device__ __forceinline__ unsigned short f2bf(float f) {
  uint32_t u = __builtin_bit_cast(uint32_t, f);
  u = (u + 0x7fffu + ((u >> 16) & 1u)) >> 16;   // RNE
  return (unsigned short)u;
}
static __device__ __forceinline__ s16x8 ldsfrag(const char* p) {
  return __builtin_bit_cast(s16x8, *reinterpret_cast<const uint4*>(p));
}

// ---------------- prep: pack Wi and Wh slices, bf16, per-column-block ----------------
// Wipk/Wpk [cj][c96][k]: c96 = gate*32+cc; gate 0=r,1=z,2=n; k = 0..511.
__global__ void prep(const float* __restrict__ Wi, const float* __restrict__ Whrz,
                     const float* __restrict__ Whn,
                     unsigned short* __restrict__ Wipk, unsigned short* __restrict__ Wpk) {
  int i = blockIdx.x * 256 + threadIdx.x;
  if (i < 786432) {
    int ck = i >> 9, k = i & 511;
    int cj = ck / 96, c96 = ck % 96;
    int g = c96 >> 5, cc = c96 & 31;
    Wipk[i] = f2bf(Wi[(size_t)k * 1536 + g * 512 + cj * 32 + cc]);
  } else {
    int j = i - 786432;
    int ck = j >> 9, k = j & 511;
    int cj = ck / 96, c96 = ck % 96;
    int g = c96 >> 5, cc = c96 & 31;
    float v = (g < 2) ? Whrz[(size_t)k * 1024 + g * 512 + cj * 32 + cc]
                      : Whn[(size_t)k * 512 + cj * 32 + cc];
    Wpk[j] = f2bf(v);
  }
}

// ---------------- tag0: slot0 <- tagged(epoch 0) h0; f32 carry <- h0 ----------
__global__ void tag0(const float* __restrict__ h0, uint32_t* __restrict__ hxt,
                     float* __restrict__ hbF) {
  int i = blockIdx.x * 512 + threadIdx.x;   // 65536
  float v = h0[i];
  hxt[i] = (uint32_t)f2bf(v);               // tag 0
  hbF[i] = v;
}

// ---------------- resets dtype probe (bool bytes vs int32) ----------------
__global__ void scanR(const int* __restrict__ r, int* __restrict__ flag) {
  int i = blockIdx.x * 256 + threadIdx.x;       // 32768 ints = 131072 bytes, safe
  unsigned int v = (unsigned int)r[i];
  if (v > 1u) atomicOr(flag, 1);
}

// ---------------- helpers ----------------
static __device__ __forceinline__ unsigned rmask16f(const int* resets, int rmode,
                                                    long long tg, int row0) {
  unsigned m = 0;
  if (rmode) {
    const unsigned char* rb = reinterpret_cast<const unsigned char*>(resets);
    uint4 u = *reinterpret_cast<const uint4*>(rb + (size_t)tg * 128 + row0);
    unsigned w0 = u.x, w1 = u.y, w2 = u.z, w3 = u.w;
#pragma unroll
    for (int b = 0; b < 4; ++b) {
      if ((w0 >> (8 * b)) & 0xFFu) m |= 1u << (0 + b);
      if ((w1 >> (8 * b)) & 0xFFu) m |= 1u << (4 + b);
      if ((w2 >> (8 * b)) & 0xFFu) m |= 1u << (8 + b);
      if ((w3 >> (8 * b)) & 0xFFu) m |= 1u << (12 + b);
    }
  } else {
    const uint4* p = reinterpret_cast<const uint4*>(resets + (size_t)tg * 128 + row0);
#pragma unroll
    for (int q = 0; q < 4; ++q) {
      uint4 u = p[q];
      if (u.x) m |= 1u << (q * 4 + 0);
      if (u.y) m |= 1u << (q * 4 + 1);
      if (u.z) m |= 1u << (q * 4 + 2);
      if (u.w) m |= 1u << (q * 4 + 3);
    }
  }
  return m;
}

// batched tag poll, 64-bit atomic loads (2 words each), retry-masked.
// All 16 words come from ONE producer block (16-col segment within its 32).
static __device__ __forceinline__ void pollTagQ(const uint32_t* src, unsigned exp,
                                                unsigned short (&v)[16]) {
  const unsigned long long* s8 = reinterpret_cast<const unsigned long long*>(src);
  bool need = true;
  for (int it = 0; it < (1 << 14); ++it) {
    if (need) {
      unsigned long long q[8];
#pragma unroll
      for (int i = 0; i < 8; ++i)
        q[i] = __hip_atomic_load(s8 + i, __ATOMIC_RELAXED, __HIP_MEMORY_SCOPE_AGENT);
      unsigned bad = 0;
#pragma unroll
      for (int i = 0; i < 8; ++i)
        bad |= (unsigned)(((q[i] >> 16) ^ (unsigned long long)exp) & 0xFFFFull)
             | (unsigned)(((q[i] >> 48) ^ (unsigned long long)exp) & 0xFFFFull);
      if (bad == 0u) {
#pragma unroll
        for (int i = 0; i < 8; ++i) {
          v[2 * i]     = (unsigned short)q[i];
          v[2 * i + 1] = (unsigned short)(q[i] >> 32);
        }
        need = false;
      }
    }
    if (__ballot(need ? 1 : 0) == 0ull) break;
    if (it >= 1) __builtin_amdgcn_s_sleep(1);
  }
}

static __device__ __forceinline__ f32x4 mfbf(uint4 wfr, s16x8 b, f32x4 c) {
  return __builtin_amdgcn_mfma_f32_16x16x32_bf16(__builtin_bit_cast(s16x8, wfr), b, c, 0, 0, 0);
}

// pack 16 f32 (4x float4) -> 2 uint4 of bf16 and store to LDS
static __device__ __forceinline__ void stageX16(char* base, int soff0, int soff1,
                                                const float4 (&xq)[4]) {
  uint4 p0, p1;
  p0.x = (uint32_t)f2bf(xq[0].x) | ((uint32_t)f2bf(xq[0].y) << 16);
  p0.y = (uint32_t)f2bf(xq[0].z) | ((uint32_t)f2bf(xq[0].w) << 16);
  p0.z = (uint32_t)f2bf(xq[1].x) | ((uint32_t)f2bf(xq[1].y) << 16);
  p0.w = (uint32_t)f2bf(xq[1].z) | ((uint32_t)f2bf(xq[1].w) << 16);
  p1.x = (uint32_t)f2bf(xq[2].x) | ((uint32_t)f2bf(xq[2].y) << 16);
  p1.y = (uint32_t)f2bf(xq[2].z) | ((uint32_t)f2bf(xq[2].w) << 16);
  p1.z = (uint32_t)f2bf(xq[3].x) | ((uint32_t)f2bf(xq[3].y) << 16);
  p1.w = (uint32_t)f2bf(xq[3].z) | ((uint32_t)f2bf(xq[3].w) << 16);
  *reinterpret_cast<uint4*>(base + soff0) = p0;
  *reinterpret_cast<uint4*>(base + soff1) = p1;
}

// ---------------- rnnB ----------------
#define RNN_SMEM (16384 + 16384 + 36864)   // Hlb + Xlb + ax[8][4][16*18]f32

__global__ __launch_bounds__(512) void rnnB(const float* __restrict__ x,
                                            const unsigned short* __restrict__ Wipk,
                                            const unsigned short* __restrict__ Wpk,
                                            const float* __restrict__ bi,
                                            const float* __restrict__ bhn,
                                            const int* __restrict__ resets,
                                            uint32_t* hxt,                 // [2][128][512]
                                            const float* __restrict__ hbF, // [128][512]
                                            const int* __restrict__ rmodep,
                                            float* __restrict__ ys,
                                            int tc) {
  extern __shared__ char smem[];
  char* Hlb = smem;                                       // 16384 B
  char* Xlb = smem + 16384;                               // 16384 B
  float* ax = reinterpret_cast<float*>(smem + 32768);     // 36864 B

  const int tid = threadIdx.x;
  const int lane = tid & 63;
  const int wv = tid >> 6;
  const int w = wv & 1, ks = wv >> 1;
  const int cj = blockIdx.x >> 3, rg = blockIdx.x & 7;
  const int ec = tid & 31, eb = tid >> 5;          // elementwise: col-in-32, row-in-16
  const int bglob = rg * 16 + eb;
  const int colglob = cj * 32 + ec;
  const int b16 = tid & 15, seg = tid >> 4;        // staging/poll: row, 16-col segment
  const int swzB = (b16 & 7) << 4;
  const int soff0 = b16 * 1024 + ((seg * 32) ^ swzB);
  const int soff1 = b16 * 1024 + ((seg * 32 + 16) ^ swzB);
  const int rmode = *rmodep;

  // MFMA read geometry (B-operand: row = lane&15, k-slice by lane>>4)
  const int rowb = lane & 15;
  const int hsw = (rowb & 7) << 4;
  const int kplusB = (lane >> 4) << 4;

  // ---- Wh + Wi fragments -> registers (once per launch) ----
  uint4 wreg[3][4], wireg[3][4];
  {
    const size_t fb = (size_t)cj * 96 * 512
                    + (size_t)(w * 16 + (lane & 15)) * 512
                    + ks * 128 + (lane >> 4) * 8;
#pragma unroll
    for (int g = 0; g < 3; ++g)
#pragma unroll
      for (int kk = 0; kk < 4; ++kk) {
        wreg[g][kk]  = *reinterpret_cast<const uint4*>(Wpk  + fb + g * 32 * 512 + kk * 32);
        wireg[g][kk] = *reinterpret_cast<const uint4*>(Wipk + fb + g * 32 * 512 + kk * 32);
      }
  }

  const float bhn_c = bhn[colglob];
  float bir3[3];
#pragma unroll
  for (int g = 0; g < 3; ++g) bir3[g] = bi[g * 512 + colglob];
  float h_old = hbF[(size_t)bglob * 512 + colglob];

  // ---- preamble: x(0) -> Xlb; prefetch x(1); poll h(0); mask(0) ----
  float4 xq[4];
  {
    const float* xr = x + (size_t)(rg * 16 + b16) * 512 + seg * 16;
#pragma unroll
    for (int q = 0; q < 4; ++q) xq[q] = *reinterpret_cast<const float4*>(xr + q * 4);
  }
  stageX16(Xlb, soff0, soff1, xq);           // X(0); visibility via first B1
  if (tc > 1) {
    const float* xr = x + ((size_t)1 * 128 + rg * 16 + b16) * 512 + seg * 16;
#pragma unroll
    for (int q = 0; q < 4; ++q) xq[q] = *reinterpret_cast<const float4*>(xr + q * 4);
  }
  unsigned short v[16];
  pollTagQ(hxt + (size_t)(rg * 16 + b16) * 512 + seg * 16, 0u, v);
  unsigned mask = rmask16f(resets, rmode, 0, rg * 16);

  for (int t = 0; t < tc; ++t) {
    // ---- stage H(t): 2 uint4 writes, reset-masked (row-uniform bit) ----
    {
      const unsigned keep = ((mask >> b16) & 1u) ? 0u : 0xFFFFFFFFu;
      uint4 p0, p1;
      p0.x = ((uint32_t)v[0] | ((uint32_t)v[1] << 16)) & keep;
      p0.y = ((uint32_t)v[2] | ((uint32_t)v[3] << 16)) & keep;
      p0.z = ((uint32_t)v[4] | ((uint32_t)v[5] << 16)) & keep;
      p0.w = ((uint32_t)v[6] | ((uint32_t)v[7] << 16)) & keep;
      p1.x = ((uint32_t)v[8] | ((uint32_t)v[9] << 16)) & keep;
      p1.y = ((uint32_t)v[10] | ((uint32_t)v[11] << 16)) & keep;
      p1.z = ((uint32_t)v[12] | ((uint32_t)v[13] << 16)) & keep;
      p1.w = ((uint32_t)v[14] | ((uint32_t)v[15] << 16)) & keep;
      *reinterpret_cast<uint4*>(Hlb + soff0) = p0;
      *reinterpret_cast<uint4*>(Hlb + soff1) = p1;
    }
    __syncthreads();  // B1: H(t) ready; X(t) (staged last poll window) ready
    // ---- 24 MFMAs: H (r,z,nh) + X (r,z,nx); weights in VGPRs ----
    f32x4 hR = (f32x4){0.f, 0.f, 0.f, 0.f}, hZ = hR, hNH = hR;
    f32x4 xpR = hR, xpZ = hR, xpN = hR;
    {
      s16x8 hf[4], xf[4];
#pragma unroll
      for (int kk = 0; kk < 4; ++kk) {
        const int kbB = (ks * 128 + kk * 32) * 2 + kplusB;
        hf[kk] = ldsfrag(Hlb + rowb * 1024 + (kbB ^ hsw));
        xf[kk] = ldsfrag(Xlb + rowb * 1024 + (kbB ^ hsw));
      }
#pragma unroll
      for (int kk = 0; kk < 4; ++kk) {
        hR  = mfbf(wreg[0][kk],  hf[kk], hR);
        hZ  = mfbf(wreg[1][kk],  hf[kk], hZ);
        hNH = mfbf(wreg[2][kk],  hf[kk], hNH);
        xpR = mfbf(wireg[0][kk], xf[kk], xpR);
        xpZ = mfbf(wireg[1][kk], xf[kk], xpZ);
        xpN = mfbf(wireg[2][kk], xf[kk], xpN);
      }
    }
    {  // partials -> ax: planes R(sum), Z(sum), NX, NH; row stride 18 (bank-safe)
      const int mh = (lane >> 4) << 2, nn = lane & 15;
      float* base = ax + (size_t)((ks * 2 + w) * 4) * 288 + nn;
      const f32x4 pR = hR + xpR, pZ = hZ + xpZ;
#pragma unroll
      for (int r = 0; r < 4; ++r) {
        base[(mh + r) * 18] = pR[r];
        base[288 + (mh + r) * 18] = pZ[r];
        base[576 + (mh + r) * 18] = xpN[r];
        base[864 + (mh + r) * 18] = hNH[r];
      }
    }
    __syncthreads();  // B2
    // ---- elementwise GRU update: one (row eb, col ec) per thread ----
    {
      const int wc = ec >> 4, mc = ec & 15;
      float s0 = 0.f, s1 = 0.f, s2x = 0.f, s2h = 0.f;
#pragma unroll
      for (int k2 = 0; k2 < 4; ++k2) {
        const float* p = ax + (size_t)((k2 * 2 + wc) * 4) * 288 + mc * 18 + eb;
        s0 += p[0]; s1 += p[288]; s2x += p[576]; s2h += p[864];
      }
      const float r = 1.f / (1.f + __expf(-(bir3[0] + s0)));
      const float z = 1.f / (1.f + __expf(-(bir3[1] + s1)));
      const float hu = ((mask >> eb) & 1u) ? 0.f : h_old;
      const float pre = (bir3[2] + s2x) + r * (s2h + bhn_c);
      const float n = 1.f - 2.f / (1.f + __expf(2.f * pre));
      float hn = (1.f - z) * n + z * hu;
      hn = fminf(1.f, fmaxf(-1.f, hn));
      // publish FIRST (critical path), then output store
      const uint32_t tagged = (((uint32_t)(t + 1) & 0xFFFFu) << 16) | (uint32_t)f2bf(hn);
      __hip_atomic_store(hxt + (size_t)((t + 1) & 1) * 65536 + (size_t)bglob * 512 + colglob,
                         tagged, __ATOMIC_RELAXED, __HIP_MEMORY_SCOPE_AGENT);
      __builtin_nontemporal_store(hn, ys + ((size_t)t * 128 + bglob) * 512 + colglob);
      h_old = hn;
    }
    // ---- poll window: NO barrier until next B1 (r9 lesson) ----
    if (t + 1 < tc) {
      stageX16(Xlb, soff0, soff1, xq);       // X(t+1); Xlb dead since B2
      if (t + 2 < tc) {                      // prefetch x(t+2)
        const float* xr = x + ((size_t)(t + 2) * 128 + rg * 16 + b16) * 512 + seg * 16;
#pragma unroll
        for (int q = 0; q < 4; ++q) xq[q] = *reinterpret_cast<const float4*>(xr + q * 4);
      }
      const unsigned nmask = rmask16f(resets, rmode, t + 1, rg * 16);
      pollTagQ(hxt + (size_t)((t + 1) & 1) * 65536 + (size_t)(rg * 16 + b16) * 512 + seg * 16,
               (unsigned)(t + 1) & 0xFFFFu, v);
      mask = nmask;
    }
  }
}

// ---------------- launch ----------------
extern "C" void kernel_launch(void* const* d_in, const int* in_sizes, int n_in,
                              void* d_out, int out_size, void* d_ws, size_t ws_size,
                              hipStream_t stream) {
  const float* h0 = (const float*)d_in[0];
  const float* ins = (const float*)d_in[1];
  const int* rst = (const int*)d_in[2];
  const float* Wi = (const float*)d_in[3];
  const float* bi = (const float*)d_in[4];
  const float* Whrz = (const float*)d_in[5];
  const float* Whn = (const float*)d_in[6];
  const float* bhn = (const float*)d_in[7];
  float* ys = (float*)d_out;

  char* ws = (char*)d_ws;
  unsigned short* Wpk = (unsigned short*)(ws);              // 1,572,864 B
  unsigned short* Wipk = (unsigned short*)(ws + 1572864);   // 1,572,864 B
  uint32_t* hxt = (uint32_t*)(ws + 3145728);                //   524,288 B ([2][128][512])
  float* hbF = (float*)(ws + 3670016);                      //   262,144 B
  int* flag = (int*)(ws + 3932160);                         //         4 B (rmode)

  hipMemsetAsync(flag, 0, 4, stream);                                  // rmode
  hipMemsetAsync(hxt, 0, 524288, stream);        // both slots -> tag 0 (replay-safe)
  tag0<<<dim3(128), dim3(512), 0, stream>>>(h0, hxt, hbF);             // slot0 = h(0)
  prep<<<dim3(6144), dim3(256), 0, stream>>>(Wi, Whrz, Whn, Wipk, Wpk);
  scanR<<<dim3(128), dim3(256), 0, stream>>>(rst, flag);
  hipFuncSetAttribute((const void*)rnnB, hipFuncAttributeMaxDynamicSharedMemorySize,
                      RNN_SMEM);
  rnnB<<<dim3(128), dim3(512), RNN_SMEM, stream>>>(ins, Wipk, Wpk, bi, bhn, rst,
                                                   hxt, hbF, flag, ys, 1024);
}